// Round 13
// baseline (289.453 us; speedup 1.0000x reference)
//
#include <hip/hip_runtime.h>
#include <hip/hip_bf16.h>
#include <math.h>

#define N_NODES 30000
#define M_PAD   30080     // 235*128
#define N_EDGES 480000
#define N_GRAPH 64
#define L_TOK   20
#define D_EMB   32
#define S_SCAL  64
#define TOT     224      // S + 5*D, = 7*32
#define H1      4
#define F1      512      // H1*C1
#define F2      128
#define CAP     128      // bucket capacity per node (max observed deg ~46)

#define NB_IN   ((N_NODES + 255) / 256)
#define NB_TR   ((TOT / 32) * (F1 / 32) + (F1 / 32) * (F2 / 32))   // 112 + 64
#define NB_SC   ((N_EDGES + 255) / 256)
#define NB_FL   ((N_NODES + 3) / 4)

typedef __attribute__((ext_vector_type(8))) short bf16x8;
typedef __attribute__((ext_vector_type(4))) float f32x4;

__device__ __forceinline__ unsigned short f2b(float f) {
    unsigned u = __float_as_uint(f);
    u += 0x7FFFu + ((u >> 16) & 1u);
    return (unsigned short)(u >> 16);
}
__device__ __forceinline__ float blo(unsigned u) { return __uint_as_float(u << 16); }
__device__ __forceinline__ float bhi(unsigned u) { return __uint_as_float(u & 0xFFFF0000u); }
__device__ __forceinline__ float elu(float x) { return (x > 0.f) ? x : expm1f(x); }

__device__ __forceinline__ void gload_lds16(const void* g, void* l) {
    __builtin_amdgcn_global_load_lds(
        (const __attribute__((address_space(1))) unsigned int*)g,
        (__attribute__((address_space(3))) unsigned int*)l, 16, 0, 0);
}

// ---------------- K1: init (deg=1, self-loop) + both weight transposes ----------------
__global__ void k1_init_transpose(int* __restrict__ deg, int* __restrict__ csr,
                                  const float* __restrict__ Wa, unsigned short* __restrict__ WaT,
                                  const float* __restrict__ Wb, unsigned short* __restrict__ WbT) {
    __shared__ float tile[32][33];
    int bid = blockIdx.x, t = threadIdx.x;
    if (bid < NB_IN) {
        int i = bid * 256 + t;
        if (i < N_NODES) {
            deg[i] = 1;
            csr[i * CAP] = i;       // self loop at slot 0
        }
        return;
    }
    bid -= NB_IN;
    const float* W; unsigned short* WT; int K, N, kb, nb;
    if (bid < (TOT / 32) * (F1 / 32)) {
        W = Wa; WT = WaT; K = TOT; N = F1;
        kb = (bid % (TOT / 32)) * 32; nb = (bid / (TOT / 32)) * 32;
    } else {
        bid -= (TOT / 32) * (F1 / 32);
        W = Wb; WT = WbT; K = F1; N = F2;
        kb = (bid % (F1 / 32)) * 32; nb = (bid / (F1 / 32)) * 32;
    }
    int r = t >> 3, c4 = (t & 7) * 4;
    float4 v = *reinterpret_cast<const float4*>(&W[(size_t)(kb + r) * N + nb + c4]);
    tile[r][c4 + 0] = v.x; tile[r][c4 + 1] = v.y;
    tile[r][c4 + 2] = v.z; tile[r][c4 + 3] = v.w;
    __syncthreads();
    ushort4 o;
    o.x = f2b(tile[c4 + 0][r]); o.y = f2b(tile[c4 + 1][r]);
    o.z = f2b(tile[c4 + 2][r]); o.w = f2b(tile[c4 + 3][r]);
    *reinterpret_cast<ushort4*>(&WT[(size_t)(nb + r) * K + kb + c4]) = o;
}

// ---------------- K2: edge scatter (bucket CSR) + feat_ln ----------------
__global__ void k2_scatter_featln(const int* __restrict__ ei, int* __restrict__ deg,
                                  int* __restrict__ csr,
                                  const float* __restrict__ xs,
                                  const int* __restrict__ xo, const int* __restrict__ xsrc,
                                  const int* __restrict__ xsink, const int* __restrict__ xstr,
                                  const int* __restrict__ xpay,
                                  const float* __restrict__ eo, const float* __restrict__ es,
                                  const float* __restrict__ ek, const float* __restrict__ eg,
                                  const float* __restrict__ ep,
                                  const float* __restrict__ lns, const float* __restrict__ lnb,
                                  unsigned short* __restrict__ x0) {
    int bid = blockIdx.x;
    if (bid < NB_SC) {
        int e = bid * 256 + threadIdx.x;
        if (e < N_EDGES) {
            int src = ei[e], dst = ei[N_EDGES + e];
            int slot = atomicAdd(&deg[dst], 1);
            if (slot < CAP) csr[dst * CAP + slot] = src;
        }
        return;
    }
    int node = (bid - NB_SC) * 4 + (threadIdx.x >> 6);
    if (node >= N_NODES) return;
    int lane = threadIdx.x & 63;
    int c = lane * 4;
    float f0 = 0.f, f1 = 0.f, f2 = 0.f, f3 = 0.f;
    if (lane < 16) {
        float4 v = *reinterpret_cast<const float4*>(&xs[(size_t)node * S_SCAL + c]);
        f0 = v.x; f1 = v.y; f2 = v.z; f3 = v.w;
    } else if (lane < 56) {
        int t = c - S_SCAL;
        int ti = t >> 5, dim = t & 31;
        const int* idx; const float* emb;
        switch (ti) {
            case 0: idx = xo;   emb = eo; break;
            case 1: idx = xsrc; emb = es; break;
            case 2: idx = xsink;emb = ek; break;
            case 3: idx = xstr; emb = eg; break;
            default:idx = xpay; emb = ep; break;
        }
        float a0 = 0.f, a1 = 0.f, a2 = 0.f, a3 = 0.f, cnt = 0.f;
        #pragma unroll
        for (int l = 0; l < L_TOK; ++l) {
            int id = idx[node * L_TOK + l];
            if (id != 0) {
                float4 e = *reinterpret_cast<const float4*>(&emb[id * D_EMB + dim]);
                a0 += e.x; a1 += e.y; a2 += e.z; a3 += e.w; cnt += 1.f;
            }
        }
        float r = 1.f / (cnt + 1e-9f);
        f0 = a0 * r; f1 = a1 * r; f2 = a2 * r; f3 = a3 * r;
    }
    float s = f0 + f1 + f2 + f3;
    float q = f0 * f0 + f1 * f1 + f2 * f2 + f3 * f3;
    #pragma unroll
    for (int off = 32; off; off >>= 1) {
        s += __shfl_xor(s, off);
        q += __shfl_xor(q, off);
    }
    float mu = s * (1.f / (float)TOT);
    float var = q * (1.f / (float)TOT) - mu * mu;
    float rs = rsqrtf(var + 1e-5f);
    if (lane < 56) {
        float4 sc = *reinterpret_cast<const float4*>(&lns[c]);
        float4 bi = *reinterpret_cast<const float4*>(&lnb[c]);
        ushort4 o;
        o.x = f2b((f0 - mu) * rs * sc.x + bi.x);
        o.y = f2b((f1 - mu) * rs * sc.y + bi.y);
        o.z = f2b((f2 - mu) * rs * sc.z + bi.z);
        o.w = f2b((f3 - mu) * rs * sc.w + bi.w);
        *reinterpret_cast<ushort4*>(&x0[(size_t)node * TOT + c]) = o;
    }
}

// ---------------- bf16 MFMA GEMM, 128x128 tile, double-buffered global_load_lds ----------------
// 2-phase pipeline (T3 minimum): stage(next) issued before compute(cur); one
// vmcnt(0)+barrier per K-tile. Fused att-prep epilogue uses PLAIN stores
// (each (row,head) owned by exactly one block since grid.y == heads).
__global__ void gemm_bf16(const unsigned short* __restrict__ A,
                          const unsigned short* __restrict__ BT,
                          unsigned short* __restrict__ C, int M, int N, int K,
                          const float* __restrict__ asrc, const float* __restrict__ adst,
                          float* __restrict__ sOut, float* __restrict__ dOut, int H) {
    __shared__ unsigned short As[2][128 * 32];
    __shared__ unsigned short Bs[2][128 * 32];
    int tid = threadIdx.x;
    int w = tid >> 6, lane = tid & 63;
    int l15 = lane & 15, kb = lane >> 4;
    int wr = w >> 1, wc = w & 1;
    int bm = blockIdx.x * 128, bn = blockIdx.y * 128;
    f32x4 acc[4][4] = {};
    int lrow = lane >> 2, lslot = lane & 3;

    auto stage = [&](int buf, int k0) {
        #pragma unroll
        for (int j = 0; j < 2; ++j) {
            int rbase = w * 16 + j * 64;
            int row = rbase + lrow;
            int scol = (lslot ^ (row & 3)) * 8;
            gload_lds16(&A[(size_t)(bm + row) * K + k0 + scol], &As[buf][rbase * 32]);
            gload_lds16(&BT[(size_t)(bn + row) * K + k0 + scol], &Bs[buf][rbase * 32]);
        }
    };
    auto compute = [&](int buf) {
        bf16x8 af[4], bf[4];
        #pragma unroll
        for (int m = 0; m < 4; ++m) {
            int row = wr * 64 + m * 16 + l15;
            af[m] = *reinterpret_cast<const bf16x8*>(&As[buf][row * 32 + (kb ^ (row & 3)) * 8]);
        }
        #pragma unroll
        for (int n = 0; n < 4; ++n) {
            int row = wc * 64 + n * 16 + l15;
            bf[n] = *reinterpret_cast<const bf16x8*>(&Bs[buf][row * 32 + (kb ^ (row & 3)) * 8]);
        }
        #pragma unroll
        for (int m = 0; m < 4; ++m)
            #pragma unroll
            for (int n = 0; n < 4; ++n)
                acc[m][n] = __builtin_amdgcn_mfma_f32_16x16x32_bf16(af[m], bf[n], acc[m][n], 0, 0, 0);
    };

    stage(0, 0);
    asm volatile("s_waitcnt vmcnt(0)" ::: "memory");
    __syncthreads();
    int cur = 0;
    for (int k0 = 32; k0 < K; k0 += 32) {
        stage(cur ^ 1, k0);          // next tile's loads fly under the MFMAs
        compute(cur);
        asm volatile("s_waitcnt vmcnt(0)" ::: "memory");
        __syncthreads();             // implies lgkmcnt(0): buf `cur` reads drained
        cur ^= 1;
    }
    compute(cur);

    #pragma unroll
    for (int m = 0; m < 4; ++m) {
        #pragma unroll
        for (int r = 0; r < 4; ++r) {
            int row = bm + wr * 64 + m * 16 + kb * 4 + r;
            if (row < M) {
                #pragma unroll
                for (int n = 0; n < 4; ++n)
                    C[(size_t)row * N + bn + wc * 64 + n * 16 + l15] = f2b(acc[m][n][r]);
            }
        }
    }
    // fused attention prep (plain stores: single writer per (row,head))
    {
        float a_s[4], a_d[4];
        #pragma unroll
        for (int n = 0; n < 4; ++n) {
            a_s[n] = asrc[bn + wc * 64 + n * 16 + l15];
            a_d[n] = adst[bn + wc * 64 + n * 16 + l15];
        }
        int head = bn / (N / H);
        #pragma unroll
        for (int m = 0; m < 4; ++m) {
            #pragma unroll
            for (int r = 0; r < 4; ++r) {
                float ps = acc[m][0][r] * a_s[0] + acc[m][1][r] * a_s[1]
                         + acc[m][2][r] * a_s[2] + acc[m][3][r] * a_s[3];
                float pd = acc[m][0][r] * a_d[0] + acc[m][1][r] * a_d[1]
                         + acc[m][2][r] * a_d[2] + acc[m][3][r] * a_d[3];
                #pragma unroll
                for (int off = 8; off >= 1; off >>= 1) {
                    ps += __shfl_xor(ps, off);
                    pd += __shfl_xor(pd, off);
                }
                if (l15 == 0) {
                    int row = bm + wr * 64 + m * 16 + kb * 4 + r;
                    if (row < M) {
                        // wc=0 and wc=1 both compute partial sums over their 64 cols;
                        // combine via LDS-free trick: wc==1 stores partial, wc==0 adds?
                        // Simpler: both halves write disjoint temp then? -> use atomicAdd
                        // fallback ONLY across the two wc halves:
                        atomicAdd(&sOut[row * H + head], ps);
                        atomicAdd(&dOut[row * H + head], pd);
                    }
                }
            }
        }
    }
}

// zero s/d accumulators (tiny)
__global__ void zero_sd(float* s1, float* d1, float* s2, float* d2) {
    int i = blockIdx.x * blockDim.x + threadIdx.x;
    if (i < N_NODES) {
        s2[i] = 0.f; d2[i] = 0.f;
        float4 z = make_float4(0.f, 0.f, 0.f, 0.f);
        *reinterpret_cast<float4*>(&s1[i * 4]) = z;
        *reinterpret_cast<float4*>(&d1[i * 4]) = z;
    }
}

// ---------------- GAT layer 1: softmax + aggregate + bias + elu (bucket CSR) ----------------
#define ACC8(v, a) \
    acc[0] += (a) * blo((v).x); acc[1] += (a) * bhi((v).x); \
    acc[2] += (a) * blo((v).y); acc[3] += (a) * bhi((v).y); \
    acc[4] += (a) * blo((v).z); acc[5] += (a) * bhi((v).z); \
    acc[6] += (a) * blo((v).w); acc[7] += (a) * bhi((v).w);

__global__ void gat1_aggregate(const unsigned short* __restrict__ h1, const float* __restrict__ s1,
                               const float* __restrict__ d1, const int* __restrict__ degA,
                               const int* __restrict__ csr, const float* __restrict__ b1,
                               unsigned short* __restrict__ x1) {
    int n = blockIdx.x, tid = threadIdx.x;
    int wave = tid >> 6, lane = tid & 63;
    int head = lane >> 4;
    int r0 = n * CAP, deg = degA[n];
    __shared__ float alpha_sh[H1][68];
    __shared__ int src_sh[64];
    __shared__ float d_n[H1];
    __shared__ float red[3][512];
    if (tid < H1) d_n[tid] = d1[n * H1 + tid];
    __syncthreads();
    float dnw = d_n[wave];
    const uint4* h1u4 = (const uint4*)h1;     // row = 64 uint4
    float acc[8] = {};

    auto gather = [&](int cnt) {
        int iA = wave, iB = wave + 4, iC = wave + 8, iD = wave + 12;
        bool hA = iA < cnt, hB = iB < cnt, hC = iC < cnt, hD = iD < cnt;
        int s; float aA, aB, aC, aD; uint4 vA, vB, vC, vD;
        if (hA) { s = __builtin_amdgcn_readfirstlane(src_sh[iA]); aA = alpha_sh[head][iA]; vA = h1u4[(size_t)s * 64 + lane]; }
        if (hB) { s = __builtin_amdgcn_readfirstlane(src_sh[iB]); aB = alpha_sh[head][iB]; vB = h1u4[(size_t)s * 64 + lane]; }
        if (hC) { s = __builtin_amdgcn_readfirstlane(src_sh[iC]); aC = alpha_sh[head][iC]; vC = h1u4[(size_t)s * 64 + lane]; }
        if (hD) { s = __builtin_amdgcn_readfirstlane(src_sh[iD]); aD = alpha_sh[head][iD]; vD = h1u4[(size_t)s * 64 + lane]; }
        while (hA) {
            {
                uint4 v = vA; float a = aA;
                iA += 16; hA = iA < cnt;
                if (hA) { s = __builtin_amdgcn_readfirstlane(src_sh[iA]); aA = alpha_sh[head][iA]; vA = h1u4[(size_t)s * 64 + lane]; }
                ACC8(v, a)
            }
            if (hB) {
                uint4 v = vB; float a = aB;
                iB += 16; hB = iB < cnt;
                if (hB) { s = __builtin_amdgcn_readfirstlane(src_sh[iB]); aB = alpha_sh[head][iB]; vB = h1u4[(size_t)s * 64 + lane]; }
                ACC8(v, a)
            }
            if (hC) {
                uint4 v = vC; float a = aC;
                iC += 16; hC = iC < cnt;
                if (hC) { s = __builtin_amdgcn_readfirstlane(src_sh[iC]); aC = alpha_sh[head][iC]; vC = h1u4[(size_t)s * 64 + lane]; }
                ACC8(v, a)
            }
            if (hD) {
                uint4 v = vD; float a = aD;
                iD += 16; hD = iD < cnt;
                if (hD) { s = __builtin_amdgcn_readfirstlane(src_sh[iD]); aD = alpha_sh[head][iD]; vD = h1u4[(size_t)s * 64 + lane]; }
                ACC8(v, a)
            }
        }
    };

    if (deg <= 64) {
        float e = -1e30f;
        if (lane < deg) {
            int src = csr[r0 + lane];
            if (wave == 0) src_sh[lane] = src;
            float ev = s1[src * H1 + wave] + dnw;
            e = (ev >= 0.f) ? ev : 0.2f * ev;
        }
        float m = e;
        #pragma unroll
        for (int off = 32; off; off >>= 1) m = fmaxf(m, __shfl_xor(m, off));
        float ex = (lane < deg) ? __expf(e - m) : 0.f;
        float den = ex;
        #pragma unroll
        for (int off = 32; off; off >>= 1) den += __shfl_xor(den, off);
        alpha_sh[wave][lane] = ex / den;
        __syncthreads();
        gather(deg);
    } else {
        float m = -1e30f;
        for (int i = lane; i < deg; i += 64) {
            int src = csr[r0 + i];
            float e = s1[src * H1 + wave] + dnw;
            e = (e >= 0.f) ? e : 0.2f * e;
            m = fmaxf(m, e);
        }
        #pragma unroll
        for (int off = 32; off; off >>= 1) m = fmaxf(m, __shfl_xor(m, off));
        float den = 0.f;
        for (int i = lane; i < deg; i += 64) {
            int src = csr[r0 + i];
            float e = s1[src * H1 + wave] + dnw;
            e = (e >= 0.f) ? e : 0.2f * e;
            den += __expf(e - m);
        }
        #pragma unroll
        for (int off = 32; off; off >>= 1) den += __shfl_xor(den, off);
        float invw = 1.f / den;
        for (int c0 = 0; c0 < deg; c0 += 64) {
            __syncthreads();
            int i = c0 + lane;
            if (i < deg) {
                int src = csr[r0 + i];
                if (wave == 0) src_sh[lane] = src;
                float e = s1[src * H1 + wave] + dnw;
                e = (e >= 0.f) ? e : 0.2f * e;
                alpha_sh[wave][lane] = __expf(e - m) * invw;
            }
            __syncthreads();
            gather(min(64, deg - c0));
        }
    }
    if (wave > 0) {
        *reinterpret_cast<float4*>(&red[wave - 1][lane * 4]) =
            make_float4(acc[0], acc[1], acc[2], acc[3]);
        *reinterpret_cast<float4*>(&red[wave - 1][256 + lane * 4]) =
            make_float4(acc[4], acc[5], acc[6], acc[7]);
    }
    __syncthreads();
    if (wave == 0) {
        #pragma unroll
        for (int w = 0; w < 3; ++w) {
            float4 p = *reinterpret_cast<float4*>(&red[w][lane * 4]);
            float4 q = *reinterpret_cast<float4*>(&red[w][256 + lane * 4]);
            acc[0] += p.x; acc[1] += p.y; acc[2] += p.z; acc[3] += p.w;
            acc[4] += q.x; acc[5] += q.y; acc[6] += q.z; acc[7] += q.w;
        }
        float4 b0 = *reinterpret_cast<const float4*>(&b1[lane * 8]);
        float4 b4 = *reinterpret_cast<const float4*>(&b1[lane * 8 + 4]);
        float v0 = elu(acc[0] + b0.x), v1 = elu(acc[1] + b0.y);
        float v2 = elu(acc[2] + b0.z), v3 = elu(acc[3] + b0.w);
        float v4 = elu(acc[4] + b4.x), v5 = elu(acc[5] + b4.y);
        float v6 = elu(acc[6] + b4.z), v7 = elu(acc[7] + b4.w);
        uint4 pk;
        pk.x = (unsigned)f2b(v0) | ((unsigned)f2b(v1) << 16);
        pk.y = (unsigned)f2b(v2) | ((unsigned)f2b(v3) << 16);
        pk.z = (unsigned)f2b(v4) | ((unsigned)f2b(v5) << 16);
        pk.w = (unsigned)f2b(v6) | ((unsigned)f2b(v7) << 16);
        ((uint4*)x1)[(size_t)n * 64 + lane] = pk;
    }
}

// ---------------- GAT layer 2 per-node output (bucket CSR, no atomics) ----------------
__global__ void gat2_node(const unsigned short* __restrict__ h2, const float* __restrict__ s2,
                          const float* __restrict__ d2, const int* __restrict__ degA,
                          const int* __restrict__ csr, const float* __restrict__ b2,
                          float* __restrict__ h2act) {
    int n = blockIdx.x, tid = threadIdx.x;   // 128 threads
    int wid = tid >> 6, lane = tid & 63;
    int grp = tid >> 4, l16 = tid & 15;
    int r0 = n * CAP, deg = degA[n];
    __shared__ float alpha_sh[128];
    __shared__ int src_sh[128];
    __shared__ float rA[2], rB[2];
    __shared__ float red[8][128];
    float dn = d2[n];
    const uint4* h2u4 = (const uint4*)h2;    // row = 16 uint4
    float acc[8] = {};

    auto gather = [&](int cnt) {
        int iA = grp, iB = grp + 8, iC = grp + 16, iD = grp + 24;
        bool hA = iA < cnt, hB = iB < cnt, hC = iC < cnt, hD = iD < cnt;
        int s; float aA, aB, aC, aD; uint4 vA, vB, vC, vD;
        if (hA) { s = src_sh[iA]; aA = alpha_sh[iA]; vA = h2u4[(size_t)s * 16 + l16]; }
        if (hB) { s = src_sh[iB]; aB = alpha_sh[iB]; vB = h2u4[(size_t)s * 16 + l16]; }
        if (hC) { s = src_sh[iC]; aC = alpha_sh[iC]; vC = h2u4[(size_t)s * 16 + l16]; }
        if (hD) { s = src_sh[iD]; aD = alpha_sh[iD]; vD = h2u4[(size_t)s * 16 + l16]; }
        while (hA) {
            {
                uint4 v = vA; float a = aA;
                iA += 32; hA = iA < cnt;
                if (hA) { s = src_sh[iA]; aA = alpha_sh[iA]; vA = h2u4[(size_t)s * 16 + l16]; }
                ACC8(v, a)
            }
            if (hB) {
                uint4 v = vB; float a = aB;
                iB += 32; hB = iB < cnt;
                if (hB) { s = src_sh[iB]; aB = alpha_sh[iB]; vB = h2u4[(size_t)s * 16 + l16]; }
                ACC8(v, a)
            }
            if (hC) {
                uint4 v = vC; float a = aC;
                iC += 32; hC = iC < cnt;
                if (hC) { s = src_sh[iC]; aC = alpha_sh[iC]; vC = h2u4[(size_t)s * 16 + l16]; }
                ACC8(v, a)
            }
            if (hD) {
                uint4 v = vD; float a = aD;
                iD += 32; hD = iD < cnt;
                if (hD) { s = src_sh[iD]; aD = alpha_sh[iD]; vD = h2u4[(size_t)s * 16 + l16]; }
                ACC8(v, a)
            }
        }
    };

    {
        float e = -1e30f;
        if (tid < deg) {
            int src = csr[r0 + tid];
            src_sh[tid] = src;
            float ev = s2[src] + dn;
            e = (ev >= 0.f) ? ev : 0.2f * ev;
        }
        float m = e;
        #pragma unroll
        for (int off = 32; off; off >>= 1) m = fmaxf(m, __shfl_xor(m, off));
        if (lane == 0) rA[wid] = m;
        __syncthreads();
        m = fmaxf(rA[0], rA[1]);
        float ex = (tid < deg) ? __expf(e - m) : 0.f;
        float den = ex;
        #pragma unroll
        for (int off = 32; off; off >>= 1) den += __shfl_xor(den, off);
        if (lane == 0) rB[wid] = den;
        __syncthreads();
        den = rB[0] + rB[1];
        alpha_sh[tid] = ex / den;
        __syncthreads();
        gather(deg);
    }
    *reinterpret_cast<float4*>(&red[grp][l16 * 4]) =
        make_float4(acc[0], acc[1], acc[2], acc[3]);
    *reinterpret_cast<float4*>(&red[grp][64 + l16 * 4]) =
        make_float4(acc[4], acc[5], acc[6], acc[7]);
    __syncthreads();
    {
        int pos = tid;
        int ch = (pos < 64) ? ((pos >> 2) * 8 + (pos & 3))
                            : (((pos - 64) >> 2) * 8 + 4 + (pos & 3));
        float s = red[0][pos] + red[1][pos] + red[2][pos] + red[3][pos]
                + red[4][pos] + red[5][pos] + red[6][pos] + red[7][pos] + b2[ch];
        h2act[(size_t)n * F2 + ch] = elu(s);
    }
}

// ---------------- per-graph max-pool (batch sorted -> contiguous ranges) ----------------
__global__ void graph_pool(const float* __restrict__ h2act, const int* __restrict__ batch,
                           float* __restrict__ out) {
    int gph = blockIdx.x;                     // 64 blocks
    int tid = threadIdx.x;                    // 256: noff = tid>>7, ch = tid&127
    __shared__ int se[2];
    __shared__ float red[128];
    if (tid < 2) {
        int target = gph + tid;
        int lo = 0, hi = N_NODES;
        while (lo < hi) { int mid = (lo + hi) >> 1; if (batch[mid] < target) lo = mid + 1; else hi = mid; }
        se[tid] = lo;
    }
    __syncthreads();
    int start = se[0], end = se[1];
    int ch = tid & 127, noff = tid >> 7;
    float m = -INFINITY;
    for (int i = start + noff; i < end; i += 2)
        m = fmaxf(m, h2act[(size_t)i * F2 + ch]);
    if (noff == 1) red[ch] = m;
    __syncthreads();
    if (noff == 0) out[gph * F2 + ch] = fmaxf(m, red[ch]);
}

// ---------------- launcher ----------------
extern "C" void kernel_launch(void* const* d_in, const int* in_sizes, int n_in,
                              void* d_out, int out_size, void* d_ws, size_t ws_size,
                              hipStream_t stream) {
    const float* x_scalar = (const float*)d_in[0];
    const int*   x_opcode = (const int*)d_in[1];
    const int*   x_source = (const int*)d_in[2];
    const int*   x_sink   = (const int*)d_in[3];
    const int*   x_string = (const int*)d_in[4];
    const int*   x_payload= (const int*)d_in[5];
    const int*   edge_idx = (const int*)d_in[6];
    const int*   batch    = (const int*)d_in[7];
    const float* emb_op   = (const float*)d_in[8];
    const float* emb_src  = (const float*)d_in[9];
    const float* emb_snk  = (const float*)d_in[10];
    const float* emb_str  = (const float*)d_in[11];
    const float* emb_pay  = (const float*)d_in[12];
    const float* ln_scale = (const float*)d_in[13];
    const float* ln_bias  = (const float*)d_in[14];
    const float* W1       = (const float*)d_in[15];
    const float* att_src1 = (const float*)d_in[16];
    const float* att_dst1 = (const float*)d_in[17];
    const float* b1       = (const float*)d_in[18];
    const float* W2       = (const float*)d_in[19];
    const float* att_src2 = (const float*)d_in[20];
    const float* att_dst2 = (const float*)d_in[21];
    const float* b2       = (const float*)d_in[22];
    float* out = (float*)d_out;

    // workspace layout
    unsigned short* x0  = (unsigned short*)d_ws;               // M_PAD*224 bf16
    unsigned short* h1  = x0 + (size_t)M_PAD * TOT;            // M_PAD*512
    unsigned short* x1  = h1 + (size_t)M_PAD * F1;             // M_PAD*512
    unsigned short* h2  = x1 + (size_t)M_PAD * F1;             // M_PAD*128
    unsigned short* W1T = h2 + (size_t)M_PAD * F2;             // 512*224
    unsigned short* W2T = W1T + (size_t)F1 * TOT;              // 128*512
    float* s1 = (float*)(W2T + (size_t)F2 * F1);               // N*4
    float* d1 = s1 + (size_t)N_NODES * H1;
    float* s2 = d1 + (size_t)N_NODES * H1;                     // N
    float* d2 = s2 + N_NODES;
    int* deg  = (int*)(d2 + N_NODES);                          // N
    int* csr  = deg + N_NODES;                                 // N*CAP
    float* h2act = (float*)x1;                                 // alias: x1 dead after gemm2

    // K1: init + both transposes; K1b: zero s/d (for epilogue cross-half atomics)
    k1_init_transpose<<<NB_IN + NB_TR, 256, 0, stream>>>(deg, csr, W1, W1T, W2, W2T);
    zero_sd<<<NB_IN, 256, 0, stream>>>(s1, d1, s2, d2);

    // K2: edge scatter + feat_ln
    k2_scatter_featln<<<NB_SC + NB_FL, 256, 0, stream>>>(edge_idx, deg, csr,
                                                         x_scalar, x_opcode, x_source,
                                                         x_sink, x_string, x_payload,
                                                         emb_op, emb_src, emb_snk, emb_str,
                                                         emb_pay, ln_scale, ln_bias, x0);

    // K3: gemm1 + fused att-prep
    dim3 g1(M_PAD / 128, F1 / 128);
    gemm_bf16<<<g1, 256, 0, stream>>>(x0, W1T, h1, N_NODES, F1, TOT,
                                      att_src1, att_dst1, s1, d1, H1);

    // K4: gat1
    gat1_aggregate<<<N_NODES, 256, 0, stream>>>(h1, s1, d1, deg, csr, b1, x1);

    // K5: gemm2 + fused att-prep
    dim3 g2(M_PAD / 128, F2 / 128);
    gemm_bf16<<<g2, 256, 0, stream>>>(x1, W2T, h2, N_NODES, F2, F1,
                                      att_src2, att_dst2, s2, d2, 1);

    // K6: gat2
    gat2_node<<<N_NODES, 128, 0, stream>>>(h2, s2, d2, deg, csr, b2, h2act);

    // K7: pool
    graph_pool<<<N_GRAPH, 256, 0, stream>>>(h2act, batch, out);
}

// Round 15
// 286.008 us; speedup vs baseline: 1.0120x; 1.0120x over previous
//
#include <hip/hip_runtime.h>
#include <hip/hip_bf16.h>
#include <math.h>

#define N_NODES 30000
#define M_PAD   30080     // 235*128
#define N_EDGES 480000
#define N_GRAPH 64
#define L_TOK   20
#define D_EMB   32
#define S_SCAL  64
#define TOT     224      // S + 5*D, = 7*32
#define H1      4
#define F1      512      // H1*C1
#define F2      128
#define CAP     128      // bucket capacity per node (max observed deg ~46)

#define NB_IN   ((N_NODES + 255) / 256)
#define NB_TR   ((TOT / 32) * (F1 / 32) + (F1 / 32) * (F2 / 32))   // 112 + 64
#define NB_SC   ((N_EDGES + 255) / 256)
#define NB_FL   ((N_NODES + 3) / 4)

typedef __attribute__((ext_vector_type(8))) short bf16x8;
typedef __attribute__((ext_vector_type(4))) float f32x4;

__device__ __forceinline__ unsigned short f2b(float f) {
    unsigned u = __float_as_uint(f);
    u += 0x7FFFu + ((u >> 16) & 1u);
    return (unsigned short)(u >> 16);
}
__device__ __forceinline__ float blo(unsigned u) { return __uint_as_float(u << 16); }
__device__ __forceinline__ float bhi(unsigned u) { return __uint_as_float(u & 0xFFFF0000u); }
__device__ __forceinline__ float elu(float x) { return (x > 0.f) ? x : expm1f(x); }

__device__ __forceinline__ void gload_lds16(const void* g, void* l) {
    __builtin_amdgcn_global_load_lds(
        (const __attribute__((address_space(1))) unsigned int*)g,
        (__attribute__((address_space(3))) unsigned int*)l, 16, 0, 0);
}

// ---------------- K1: init (deg=1, self-loop, zero s/d) + both weight transposes ----------------
__global__ void k1_init_transpose(int* __restrict__ deg, int* __restrict__ csr,
                                  float* __restrict__ s1, float* __restrict__ d1,
                                  float* __restrict__ s2, float* __restrict__ d2,
                                  const float* __restrict__ Wa, unsigned short* __restrict__ WaT,
                                  const float* __restrict__ Wb, unsigned short* __restrict__ WbT) {
    __shared__ float tile[32][33];
    int bid = blockIdx.x, t = threadIdx.x;
    if (bid < NB_IN) {
        int i = bid * 256 + t;
        if (i < N_NODES) {
            deg[i] = 1;
            csr[i * CAP] = i;       // self loop at slot 0
            s2[i] = 0.f; d2[i] = 0.f;
            float4 z = make_float4(0.f, 0.f, 0.f, 0.f);
            *reinterpret_cast<float4*>(&s1[i * 4]) = z;
            *reinterpret_cast<float4*>(&d1[i * 4]) = z;
        }
        return;
    }
    bid -= NB_IN;
    const float* W; unsigned short* WT; int K, N, kb, nb;
    if (bid < (TOT / 32) * (F1 / 32)) {
        W = Wa; WT = WaT; K = TOT; N = F1;
        kb = (bid % (TOT / 32)) * 32; nb = (bid / (TOT / 32)) * 32;
    } else {
        bid -= (TOT / 32) * (F1 / 32);
        W = Wb; WT = WbT; K = F1; N = F2;
        kb = (bid % (F1 / 32)) * 32; nb = (bid / (F1 / 32)) * 32;
    }
    int r = t >> 3, c4 = (t & 7) * 4;
    float4 v = *reinterpret_cast<const float4*>(&W[(size_t)(kb + r) * N + nb + c4]);
    tile[r][c4 + 0] = v.x; tile[r][c4 + 1] = v.y;
    tile[r][c4 + 2] = v.z; tile[r][c4 + 3] = v.w;
    __syncthreads();
    ushort4 o;
    o.x = f2b(tile[c4 + 0][r]); o.y = f2b(tile[c4 + 1][r]);
    o.z = f2b(tile[c4 + 2][r]); o.w = f2b(tile[c4 + 3][r]);
    *reinterpret_cast<ushort4*>(&WT[(size_t)(nb + r) * K + kb + c4]) = o;
}

// ---------------- K2: edge scatter (bucket CSR) + feat_ln ----------------
__global__ void k2_scatter_featln(const int* __restrict__ ei, int* __restrict__ deg,
                                  int* __restrict__ csr,
                                  const float* __restrict__ xs,
                                  const int* __restrict__ xo, const int* __restrict__ xsrc,
                                  const int* __restrict__ xsink, const int* __restrict__ xstr,
                                  const int* __restrict__ xpay,
                                  const float* __restrict__ eo, const float* __restrict__ es,
                                  const float* __restrict__ ek, const float* __restrict__ eg,
                                  const float* __restrict__ ep,
                                  const float* __restrict__ lns, const float* __restrict__ lnb,
                                  unsigned short* __restrict__ x0) {
    int bid = blockIdx.x;
    if (bid < NB_SC) {
        int e = bid * 256 + threadIdx.x;
        if (e < N_EDGES) {
            int src = ei[e], dst = ei[N_EDGES + e];
            int slot = atomicAdd(&deg[dst], 1);
            if (slot < CAP) csr[dst * CAP + slot] = src;
        }
        return;
    }
    int node = (bid - NB_SC) * 4 + (threadIdx.x >> 6);
    if (node >= N_NODES) return;
    int lane = threadIdx.x & 63;
    int c = lane * 4;
    float f0 = 0.f, f1 = 0.f, f2 = 0.f, f3 = 0.f;
    if (lane < 16) {
        float4 v = *reinterpret_cast<const float4*>(&xs[(size_t)node * S_SCAL + c]);
        f0 = v.x; f1 = v.y; f2 = v.z; f3 = v.w;
    } else if (lane < 56) {
        int t = c - S_SCAL;
        int ti = t >> 5, dim = t & 31;
        const int* idx; const float* emb;
        switch (ti) {
            case 0: idx = xo;   emb = eo; break;
            case 1: idx = xsrc; emb = es; break;
            case 2: idx = xsink;emb = ek; break;
            case 3: idx = xstr; emb = eg; break;
            default:idx = xpay; emb = ep; break;
        }
        float a0 = 0.f, a1 = 0.f, a2 = 0.f, a3 = 0.f, cnt = 0.f;
        #pragma unroll
        for (int l = 0; l < L_TOK; ++l) {
            int id = idx[node * L_TOK + l];
            if (id != 0) {
                float4 e = *reinterpret_cast<const float4*>(&emb[id * D_EMB + dim]);
                a0 += e.x; a1 += e.y; a2 += e.z; a3 += e.w; cnt += 1.f;
            }
        }
        float r = 1.f / (cnt + 1e-9f);
        f0 = a0 * r; f1 = a1 * r; f2 = a2 * r; f3 = a3 * r;
    }
    float s = f0 + f1 + f2 + f3;
    float q = f0 * f0 + f1 * f1 + f2 * f2 + f3 * f3;
    #pragma unroll
    for (int off = 32; off; off >>= 1) {
        s += __shfl_xor(s, off);
        q += __shfl_xor(q, off);
    }
    float mu = s * (1.f / (float)TOT);
    float var = q * (1.f / (float)TOT) - mu * mu;
    float rs = rsqrtf(var + 1e-5f);
    if (lane < 56) {
        float4 sc = *reinterpret_cast<const float4*>(&lns[c]);
        float4 bi = *reinterpret_cast<const float4*>(&lnb[c]);
        ushort4 o;
        o.x = f2b((f0 - mu) * rs * sc.x + bi.x);
        o.y = f2b((f1 - mu) * rs * sc.y + bi.y);
        o.z = f2b((f2 - mu) * rs * sc.z + bi.z);
        o.w = f2b((f3 - mu) * rs * sc.w + bi.w);
        *reinterpret_cast<ushort4*>(&x0[(size_t)node * TOT + c]) = o;
    }
}

// ---------------- bf16 MFMA GEMM, 128x128 tile, double-buffered global_load_lds ----------------
__global__ void gemm_bf16(const unsigned short* __restrict__ A,
                          const unsigned short* __restrict__ BT,
                          unsigned short* __restrict__ C, int M, int N, int K,
                          const float* __restrict__ asrc, const float* __restrict__ adst,
                          float* __restrict__ sOut, float* __restrict__ dOut, int H) {
    __shared__ unsigned short As[2][128 * 32];
    __shared__ unsigned short Bs[2][128 * 32];
    int tid = threadIdx.x;
    int w = tid >> 6, lane = tid & 63;
    int l15 = lane & 15, kb = lane >> 4;
    int wr = w >> 1, wc = w & 1;
    int bm = blockIdx.x * 128, bn = blockIdx.y * 128;
    f32x4 acc[4][4] = {};
    int lrow = lane >> 2, lslot = lane & 3;

    auto stage = [&](int buf, int k0) {
        #pragma unroll
        for (int j = 0; j < 2; ++j) {
            int rbase = w * 16 + j * 64;
            int row = rbase + lrow;
            int scol = (lslot ^ (row & 3)) * 8;
            gload_lds16(&A[(size_t)(bm + row) * K + k0 + scol], &As[buf][rbase * 32]);
            gload_lds16(&BT[(size_t)(bn + row) * K + k0 + scol], &Bs[buf][rbase * 32]);
        }
    };
    auto compute = [&](int buf) {
        bf16x8 af[4], bf[4];
        #pragma unroll
        for (int m = 0; m < 4; ++m) {
            int row = wr * 64 + m * 16 + l15;
            af[m] = *reinterpret_cast<const bf16x8*>(&As[buf][row * 32 + (kb ^ (row & 3)) * 8]);
        }
        #pragma unroll
        for (int n = 0; n < 4; ++n) {
            int row = wc * 64 + n * 16 + l15;
            bf[n] = *reinterpret_cast<const bf16x8*>(&Bs[buf][row * 32 + (kb ^ (row & 3)) * 8]);
        }
        #pragma unroll
        for (int m = 0; m < 4; ++m)
            #pragma unroll
            for (int n = 0; n < 4; ++n)
                acc[m][n] = __builtin_amdgcn_mfma_f32_16x16x32_bf16(af[m], bf[n], acc[m][n], 0, 0, 0);
    };

    stage(0, 0);
    asm volatile("s_waitcnt vmcnt(0)" ::: "memory");
    __syncthreads();
    int cur = 0;
    for (int k0 = 32; k0 < K; k0 += 32) {
        stage(cur ^ 1, k0);
        compute(cur);
        asm volatile("s_waitcnt vmcnt(0)" ::: "memory");
        __syncthreads();
        cur ^= 1;
    }
    compute(cur);

    #pragma unroll
    for (int m = 0; m < 4; ++m) {
        #pragma unroll
        for (int r = 0; r < 4; ++r) {
            int row = bm + wr * 64 + m * 16 + kb * 4 + r;
            if (row < M) {
                #pragma unroll
                for (int n = 0; n < 4; ++n)
                    C[(size_t)row * N + bn + wc * 64 + n * 16 + l15] = f2b(acc[m][n][r]);
            }
        }
    }
    // fused attention prep (atomics combine the two wc halves)
    {
        float a_s[4], a_d[4];
        #pragma unroll
        for (int n = 0; n < 4; ++n) {
            a_s[n] = asrc[bn + wc * 64 + n * 16 + l15];
            a_d[n] = adst[bn + wc * 64 + n * 16 + l15];
        }
        int head = bn / (N / H);
        #pragma unroll
        for (int m = 0; m < 4; ++m) {
            #pragma unroll
            for (int r = 0; r < 4; ++r) {
                float ps = acc[m][0][r] * a_s[0] + acc[m][1][r] * a_s[1]
                         + acc[m][2][r] * a_s[2] + acc[m][3][r] * a_s[3];
                float pd = acc[m][0][r] * a_d[0] + acc[m][1][r] * a_d[1]
                         + acc[m][2][r] * a_d[2] + acc[m][3][r] * a_d[3];
                #pragma unroll
                for (int off = 8; off >= 1; off >>= 1) {
                    ps += __shfl_xor(ps, off);
                    pd += __shfl_xor(pd, off);
                }
                if (l15 == 0) {
                    int row = bm + wr * 64 + m * 16 + kb * 4 + r;
                    if (row < M) {
                        atomicAdd(&sOut[row * H + head], ps);
                        atomicAdd(&dOut[row * H + head], pd);
                    }
                }
            }
        }
    }
}

// ---------------- GAT layer 1: softmax + aggregate + bias + elu (bucket CSR) ----------------
#define ACC8(v, a) \
    acc[0] += (a) * blo((v).x); acc[1] += (a) * bhi((v).x); \
    acc[2] += (a) * blo((v).y); acc[3] += (a) * bhi((v).y); \
    acc[4] += (a) * blo((v).z); acc[5] += (a) * bhi((v).z); \
    acc[6] += (a) * blo((v).w); acc[7] += (a) * bhi((v).w);

__global__ void gat1_aggregate(const unsigned short* __restrict__ h1, const float* __restrict__ s1,
                               const float* __restrict__ d1, const int* __restrict__ degA,
                               const int* __restrict__ csr, const float* __restrict__ b1,
                               unsigned short* __restrict__ x1) {
    int n = blockIdx.x, tid = threadIdx.x;
    int wave = tid >> 6, lane = tid & 63;
    int head = lane >> 4;
    int r0 = n * CAP, deg = degA[n];
    __shared__ float alpha_sh[H1][68];
    __shared__ int src_sh[64];
    __shared__ float d_n[H1];
    __shared__ float red[3][512];
    if (tid < H1) d_n[tid] = d1[n * H1 + tid];
    __syncthreads();
    float dnw = d_n[wave];
    const uint4* h1u4 = (const uint4*)h1;     // row = 64 uint4
    float acc[8] = {};

    auto gather = [&](int cnt) {
        int iA = wave, iB = wave + 4, iC = wave + 8, iD = wave + 12;
        bool hA = iA < cnt, hB = iB < cnt, hC = iC < cnt, hD = iD < cnt;
        int s; float aA, aB, aC, aD; uint4 vA, vB, vC, vD;
        if (hA) { s = __builtin_amdgcn_readfirstlane(src_sh[iA]); aA = alpha_sh[head][iA]; vA = h1u4[(size_t)s * 64 + lane]; }
        if (hB) { s = __builtin_amdgcn_readfirstlane(src_sh[iB]); aB = alpha_sh[head][iB]; vB = h1u4[(size_t)s * 64 + lane]; }
        if (hC) { s = __builtin_amdgcn_readfirstlane(src_sh[iC]); aC = alpha_sh[head][iC]; vC = h1u4[(size_t)s * 64 + lane]; }
        if (hD) { s = __builtin_amdgcn_readfirstlane(src_sh[iD]); aD = alpha_sh[head][iD]; vD = h1u4[(size_t)s * 64 + lane]; }
        while (hA) {
            {
                uint4 v = vA; float a = aA;
                iA += 16; hA = iA < cnt;
                if (hA) { s = __builtin_amdgcn_readfirstlane(src_sh[iA]); aA = alpha_sh[head][iA]; vA = h1u4[(size_t)s * 64 + lane]; }
                ACC8(v, a)
            }
            if (hB) {
                uint4 v = vB; float a = aB;
                iB += 16; hB = iB < cnt;
                if (hB) { s = __builtin_amdgcn_readfirstlane(src_sh[iB]); aB = alpha_sh[head][iB]; vB = h1u4[(size_t)s * 64 + lane]; }
                ACC8(v, a)
            }
            if (hC) {
                uint4 v = vC; float a = aC;
                iC += 16; hC = iC < cnt;
                if (hC) { s = __builtin_amdgcn_readfirstlane(src_sh[iC]); aC = alpha_sh[head][iC]; vC = h1u4[(size_t)s * 64 + lane]; }
                ACC8(v, a)
            }
            if (hD) {
                uint4 v = vD; float a = aD;
                iD += 16; hD = iD < cnt;
                if (hD) { s = __builtin_amdgcn_readfirstlane(src_sh[iD]); aD = alpha_sh[head][iD]; vD = h1u4[(size_t)s * 64 + lane]; }
                ACC8(v, a)
            }
        }
    };

    if (deg <= 64) {
        float e = -1e30f;
        if (lane < deg) {
            int src = csr[r0 + lane];
            if (wave == 0) src_sh[lane] = src;
            float ev = s1[src * H1 + wave] + dnw;
            e = (ev >= 0.f) ? ev : 0.2f * ev;
        }
        float m = e;
        #pragma unroll
        for (int off = 32; off; off >>= 1) m = fmaxf(m, __shfl_xor(m, off));
        float ex = (lane < deg) ? __expf(e - m) : 0.f;
        float den = ex;
        #pragma unroll
        for (int off = 32; off; off >>= 1) den += __shfl_xor(den, off);
        alpha_sh[wave][lane] = ex / den;
        __syncthreads();
        gather(deg);
    } else {
        float m = -1e30f;
        for (int i = lane; i < deg; i += 64) {
            int src = csr[r0 + i];
            float e = s1[src * H1 + wave] + dnw;
            e = (e >= 0.f) ? e : 0.2f * e;
            m = fmaxf(m, e);
        }
        #pragma unroll
        for (int off = 32; off; off >>= 1) m = fmaxf(m, __shfl_xor(m, off));
        float den = 0.f;
        for (int i = lane; i < deg; i += 64) {
            int src = csr[r0 + i];
            float e = s1[src * H1 + wave] + dnw;
            e = (e >= 0.f) ? e : 0.2f * e;
            den += __expf(e - m);
        }
        #pragma unroll
        for (int off = 32; off; off >>= 1) den += __shfl_xor(den, off);
        float invw = 1.f / den;
        for (int c0 = 0; c0 < deg; c0 += 64) {
            __syncthreads();
            int i = c0 + lane;
            if (i < deg) {
                int src = csr[r0 + i];
                if (wave == 0) src_sh[lane] = src;
                float e = s1[src * H1 + wave] + dnw;
                e = (e >= 0.f) ? e : 0.2f * e;
                alpha_sh[wave][lane] = __expf(e - m) * invw;
            }
            __syncthreads();
            gather(min(64, deg - c0));
        }
    }
    if (wave > 0) {
        *reinterpret_cast<float4*>(&red[wave - 1][lane * 4]) =
            make_float4(acc[0], acc[1], acc[2], acc[3]);
        *reinterpret_cast<float4*>(&red[wave - 1][256 + lane * 4]) =
            make_float4(acc[4], acc[5], acc[6], acc[7]);
    }
    __syncthreads();
    if (wave == 0) {
        #pragma unroll
        for (int w = 0; w < 3; ++w) {
            float4 p = *reinterpret_cast<float4*>(&red[w][lane * 4]);
            float4 q = *reinterpret_cast<float4*>(&red[w][256 + lane * 4]);
            acc[0] += p.x; acc[1] += p.y; acc[2] += p.z; acc[3] += p.w;
            acc[4] += q.x; acc[5] += q.y; acc[6] += q.z; acc[7] += q.w;
        }
        float4 b0 = *reinterpret_cast<const float4*>(&b1[lane * 8]);
        float4 b4 = *reinterpret_cast<const float4*>(&b1[lane * 8 + 4]);
        float v0 = elu(acc[0] + b0.x), v1 = elu(acc[1] + b0.y);
        float v2 = elu(acc[2] + b0.z), v3 = elu(acc[3] + b0.w);
        float v4 = elu(acc[4] + b4.x), v5 = elu(acc[5] + b4.y);
        float v6 = elu(acc[6] + b4.z), v7 = elu(acc[7] + b4.w);
        uint4 pk;
        pk.x = (unsigned)f2b(v0) | ((unsigned)f2b(v1) << 16);
        pk.y = (unsigned)f2b(v2) | ((unsigned)f2b(v3) << 16);
        pk.z = (unsigned)f2b(v4) | ((unsigned)f2b(v5) << 16);
        pk.w = (unsigned)f2b(v6) | ((unsigned)f2b(v7) << 16);
        ((uint4*)x1)[(size_t)n * 64 + lane] = pk;
    }
}

// ---------------- GAT layer 2 per-node output (bucket CSR, no atomics) ----------------
__global__ void gat2_node(const unsigned short* __restrict__ h2, const float* __restrict__ s2,
                          const float* __restrict__ d2, const int* __restrict__ degA,
                          const int* __restrict__ csr, const float* __restrict__ b2,
                          float* __restrict__ h2act) {
    int n = blockIdx.x, tid = threadIdx.x;   // 128 threads
    int wid = tid >> 6, lane = tid & 63;
    int grp = tid >> 4, l16 = tid & 15;
    int r0 = n * CAP, deg = degA[n];
    __shared__ float alpha_sh[128];
    __shared__ int src_sh[128];
    __shared__ float rA[2], rB[2];
    __shared__ float red[8][128];
    float dn = d2[n];
    const uint4* h2u4 = (const uint4*)h2;    // row = 16 uint4
    float acc[8] = {};

    auto gather = [&](int cnt) {
        int iA = grp, iB = grp + 8, iC = grp + 16, iD = grp + 24;
        bool hA = iA < cnt, hB = iB < cnt, hC = iC < cnt, hD = iD < cnt;
        int s; float aA, aB, aC, aD; uint4 vA, vB, vC, vD;
        if (hA) { s = src_sh[iA]; aA = alpha_sh[iA]; vA = h2u4[(size_t)s * 16 + l16]; }
        if (hB) { s = src_sh[iB]; aB = alpha_sh[iB]; vB = h2u4[(size_t)s * 16 + l16]; }
        if (hC) { s = src_sh[iC]; aC = alpha_sh[iC]; vC = h2u4[(size_t)s * 16 + l16]; }
        if (hD) { s = src_sh[iD]; aD = alpha_sh[iD]; vD = h2u4[(size_t)s * 16 + l16]; }
        while (hA) {
            {
                uint4 v = vA; float a = aA;
                iA += 32; hA = iA < cnt;
                if (hA) { s = src_sh[iA]; aA = alpha_sh[iA]; vA = h2u4[(size_t)s * 16 + l16]; }
                ACC8(v, a)
            }
            if (hB) {
                uint4 v = vB; float a = aB;
                iB += 32; hB = iB < cnt;
                if (hB) { s = src_sh[iB]; aB = alpha_sh[iB]; vB = h2u4[(size_t)s * 16 + l16]; }
                ACC8(v, a)
            }
            if (hC) {
                uint4 v = vC; float a = aC;
                iC += 32; hC = iC < cnt;
                if (hC) { s = src_sh[iC]; aC = alpha_sh[iC]; vC = h2u4[(size_t)s * 16 + l16]; }
                ACC8(v, a)
            }
            if (hD) {
                uint4 v = vD; float a = aD;
                iD += 32; hD = iD < cnt;
                if (hD) { s = src_sh[iD]; aD = alpha_sh[iD]; vD = h2u4[(size_t)s * 16 + l16]; }
                ACC8(v, a)
            }
        }
    };

    {
        float e = -1e30f;
        if (tid < deg) {
            int src = csr[r0 + tid];
            src_sh[tid] = src;
            float ev = s2[src] + dn;
            e = (ev >= 0.f) ? ev : 0.2f * ev;
        }
        float m = e;
        #pragma unroll
        for (int off = 32; off; off >>= 1) m = fmaxf(m, __shfl_xor(m, off));
        if (lane == 0) rA[wid] = m;
        __syncthreads();
        m = fmaxf(rA[0], rA[1]);
        float ex = (tid < deg) ? __expf(e - m) : 0.f;
        float den = ex;
        #pragma unroll
        for (int off = 32; off; off >>= 1) den += __shfl_xor(den, off);
        if (lane == 0) rB[wid] = den;
        __syncthreads();
        den = rB[0] + rB[1];
        alpha_sh[tid] = ex / den;
        __syncthreads();
        gather(deg);
    }
    *reinterpret_cast<float4*>(&red[grp][l16 * 4]) =
        make_float4(acc[0], acc[1], acc[2], acc[3]);
    *reinterpret_cast<float4*>(&red[grp][64 + l16 * 4]) =
        make_float4(acc[4], acc[5], acc[6], acc[7]);
    __syncthreads();
    {
        int pos = tid;
        int ch = (pos < 64) ? ((pos >> 2) * 8 + (pos & 3))
                            : (((pos - 64) >> 2) * 8 + 4 + (pos & 3));
        float s = red[0][pos] + red[1][pos] + red[2][pos] + red[3][pos]
                + red[4][pos] + red[5][pos] + red[6][pos] + red[7][pos] + b2[ch];
        h2act[(size_t)n * F2 + ch] = elu(s);
    }
}

// ---------------- per-graph max-pool (batch sorted -> contiguous ranges) ----------------
__global__ void graph_pool(const float* __restrict__ h2act, const int* __restrict__ batch,
                           float* __restrict__ out) {
    int gph = blockIdx.x;                     // 64 blocks
    int tid = threadIdx.x;                    // 256: noff = tid>>7, ch = tid&127
    __shared__ int se[2];
    __shared__ float red[128];
    if (tid < 2) {
        int target = gph + tid;
        int lo = 0, hi = N_NODES;
        while (lo < hi) { int mid = (lo + hi) >> 1; if (batch[mid] < target) lo = mid + 1; else hi = mid; }
        se[tid] = lo;
    }
    __syncthreads();
    int start = se[0], end = se[1];
    int ch = tid & 127, noff = tid >> 7;
    float m = -INFINITY;
    for (int i = start + noff; i < end; i += 2)
        m = fmaxf(m, h2act[(size_t)i * F2 + ch]);
    if (noff == 1) red[ch] = m;
    __syncthreads();
    if (noff == 0) out[gph * F2 + ch] = fmaxf(m, red[ch]);
}

// ---------------- launcher ----------------
extern "C" void kernel_launch(void* const* d_in, const int* in_sizes, int n_in,
                              void* d_out, int out_size, void* d_ws, size_t ws_size,
                              hipStream_t stream) {
    const float* x_scalar = (const float*)d_in[0];
    const int*   x_opcode = (const int*)d_in[1];
    const int*   x_source = (const int*)d_in[2];
    const int*   x_sink   = (const int*)d_in[3];
    const int*   x_string = (const int*)d_in[4];
    const int*   x_payload= (const int*)d_in[5];
    const int*   edge_idx = (const int*)d_in[6];
    const int*   batch    = (const int*)d_in[7];
    const float* emb_op   = (const float*)d_in[8];
    const float* emb_src  = (const float*)d_in[9];
    const float* emb_snk  = (const float*)d_in[10];
    const float* emb_str  = (const float*)d_in[11];
    const float* emb_pay  = (const float*)d_in[12];
    const float* ln_scale = (const float*)d_in[13];
    const float* ln_bias  = (const float*)d_in[14];
    const float* W1       = (const float*)d_in[15];
    const float* att_src1 = (const float*)d_in[16];
    const float* att_dst1 = (const float*)d_in[17];
    const float* b1       = (const float*)d_in[18];
    const float* W2       = (const float*)d_in[19];
    const float* att_src2 = (const float*)d_in[20];
    const float* att_dst2 = (const float*)d_in[21];
    const float* b2       = (const float*)d_in[22];
    float* out = (float*)d_out;

    // workspace layout
    unsigned short* x0  = (unsigned short*)d_ws;               // M_PAD*224 bf16
    unsigned short* h1  = x0 + (size_t)M_PAD * TOT;            // M_PAD*512
    unsigned short* x1  = h1 + (size_t)M_PAD * F1;             // M_PAD*512
    unsigned short* h2  = x1 + (size_t)M_PAD * F1;             // M_PAD*128
    unsigned short* W1T = h2 + (size_t)M_PAD * F2;             // 512*224
    unsigned short* W2T = W1T + (size_t)F1 * TOT;              // 128*512
    float* s1 = (float*)(W2T + (size_t)F2 * F1);               // N*4
    float* d1 = s1 + (size_t)N_NODES * H1;
    float* s2 = d1 + (size_t)N_NODES * H1;                     // N
    float* d2 = s2 + N_NODES;
    int* deg  = (int*)(d2 + N_NODES);                          // N
    int* csr  = deg + N_NODES;                                 // N*CAP
    float* h2act = (float*)x1;                                 // alias: x1 dead after gemm2

    // K1: init + zero s/d + both transposes
    k1_init_transpose<<<NB_IN + NB_TR, 256, 0, stream>>>(deg, csr, s1, d1, s2, d2,
                                                         W1, W1T, W2, W2T);

    // K2: edge scatter + feat_ln
    k2_scatter_featln<<<NB_SC + NB_FL, 256, 0, stream>>>(edge_idx, deg, csr,
                                                         x_scalar, x_opcode, x_source,
                                                         x_sink, x_string, x_payload,
                                                         emb_op, emb_src, emb_snk, emb_str,
                                                         emb_pay, ln_scale, ln_bias, x0);

    // K3: gemm1 + fused att-prep
    dim3 g1(M_PAD / 128, F1 / 128);
    gemm_bf16<<<g1, 256, 0, stream>>>(x0, W1T, h1, N_NODES, F1, TOT,
                                      att_src1, att_dst1, s1, d1, H1);

    // K4: gat1
    gat1_aggregate<<<N_NODES, 256, 0, stream>>>(h1, s1, d1, deg, csr, b1, x1);

    // K5: gemm2 + fused att-prep
    dim3 g2(M_PAD / 128, F2 / 128);
    gemm_bf16<<<g2, 256, 0, stream>>>(x1, W2T, h2, N_NODES, F2, F1,
                                      att_src2, att_dst2, s2, d2, 1);

    // K6: gat2
    gat2_node<<<N_NODES, 128, 0, stream>>>(h2, s2, d2, deg, csr, b2, h2act);

    // K7: pool
    graph_pool<<<N_GRAPH, 256, 0, stream>>>(h2act, batch, out);
}